// Round 1
// 501.232 us; speedup vs baseline: 1.7070x; 1.7070x over previous
//
#include <hip/hip_runtime.h>

// l=32, m=4096, n=512 fp32. Rows (131072) independent; n strictly sequential.
//   x = (input - min) / (max - min);  w[0]=1; w[k] = w[k-1] + a/w[k-1] - b*x[k-1]
// NUMERICS: recurrence is chaotic (absmax 192 vs threshold 233) — keep the
// exact expression ((w + a/w) - b*((x-mn)/denom)), IEEE div, contract off.
//
// R1: LDS-staged tiles fixed HBM amplification (1.9GB -> 512MB). 855us.
// R2 (this round), two fixes from counters:
//  (a) minmax was 410us at 330 GB/s, VALUBusy 3.5%: tail-bound by 32K contended
//      same-address atomics (4096 blocks x 4 waves x 2). -> two-stage reduction:
//      per-block partials to workspace, tiny second kernel. Zero atomics.
//  (b) recur blocks are single-wave, but had 3x __syncthreads per tile; each
//      barrier forces s_waitcnt vmcnt(0) lgkmcnt(0) -> 48 full drains/block,
//      full HBM latency exposed every 32 columns. DS ops from one wave complete
//      in order, so 1-wave LDS exchange needs NO barrier. Drop all barriers and
//      add register ping-pong prefetch (load tile t+1 while computing t):
//      stores/loads stay in flight across tiles, never drained.

#define ROWS 131072
#define NCOL 512
#define BROWS 64          // rows per (single-wave) block
#define TCOLS 32          // tile width in floats
#define NTILES (NCOL / TCOLS)
#define LDS_STRIDE 33     // +1 pad: bank = (row + col) % 32 -> 2-way max (free)
#define MM_BLOCKS 1024    // minmax grid; partials = 2*MM_BLOCKS u32 in ws[2..]

__device__ __forceinline__ unsigned f2key(float f) {
    unsigned u = __float_as_uint(f);
    return (u & 0x80000000u) ? ~u : (u | 0x80000000u);  // monotone float->uint
}
__device__ __forceinline__ float key2f(unsigned k) {
    unsigned u = (k & 0x80000000u) ? (k & 0x7fffffffu) : ~k;
    return __uint_as_float(u);
}

__global__ void init_ws_kernel(unsigned* ws) {
    ws[0] = 0xFFFFFFFFu;  // min key accumulator (atomic-fallback path only)
    ws[1] = 0u;           // max key accumulator
}

// Stage 1: grid-stride scan, wave shfl-reduce, block LDS-reduce, then either
// write per-block partial (two-stage path) or one atomic pair (fallback).
__global__ __launch_bounds__(256) void minmax_part(
        const float4* __restrict__ in, unsigned* __restrict__ ws, int n4,
        int use_atomic) {
    unsigned mnk = 0xFFFFFFFFu, mxk = 0u;
    int idx = blockIdx.x * blockDim.x + threadIdx.x;
    int stride = gridDim.x * blockDim.x;
    int i = idx;
    // 4x manual unroll for MLP (n4 = 16.7M, 262144 threads -> 64 iters, exact)
    for (; i + 3 * stride < n4; i += 4 * stride) {
        float4 v0 = in[i];
        float4 v1 = in[i + stride];
        float4 v2 = in[i + 2 * stride];
        float4 v3 = in[i + 3 * stride];
        unsigned k;
        k = f2key(v0.x); mnk = min(mnk, k); mxk = max(mxk, k);
        k = f2key(v0.y); mnk = min(mnk, k); mxk = max(mxk, k);
        k = f2key(v0.z); mnk = min(mnk, k); mxk = max(mxk, k);
        k = f2key(v0.w); mnk = min(mnk, k); mxk = max(mxk, k);
        k = f2key(v1.x); mnk = min(mnk, k); mxk = max(mxk, k);
        k = f2key(v1.y); mnk = min(mnk, k); mxk = max(mxk, k);
        k = f2key(v1.z); mnk = min(mnk, k); mxk = max(mxk, k);
        k = f2key(v1.w); mnk = min(mnk, k); mxk = max(mxk, k);
        k = f2key(v2.x); mnk = min(mnk, k); mxk = max(mxk, k);
        k = f2key(v2.y); mnk = min(mnk, k); mxk = max(mxk, k);
        k = f2key(v2.z); mnk = min(mnk, k); mxk = max(mxk, k);
        k = f2key(v2.w); mnk = min(mnk, k); mxk = max(mxk, k);
        k = f2key(v3.x); mnk = min(mnk, k); mxk = max(mxk, k);
        k = f2key(v3.y); mnk = min(mnk, k); mxk = max(mxk, k);
        k = f2key(v3.z); mnk = min(mnk, k); mxk = max(mxk, k);
        k = f2key(v3.w); mnk = min(mnk, k); mxk = max(mxk, k);
    }
    for (; i < n4; i += stride) {
        float4 v = in[i];
        unsigned k0 = f2key(v.x), k1 = f2key(v.y), k2 = f2key(v.z), k3 = f2key(v.w);
        mnk = min(mnk, min(min(k0, k1), min(k2, k3)));
        mxk = max(mxk, max(max(k0, k1), max(k2, k3)));
    }
    // wave (64-lane) reduce
    for (int off = 32; off; off >>= 1) {
        mnk = min(mnk, (unsigned)__shfl_down((int)mnk, off));
        mxk = max(mxk, (unsigned)__shfl_down((int)mxk, off));
    }
    __shared__ unsigned smn[4], smx[4];
    int wv = threadIdx.x >> 6;
    if ((threadIdx.x & 63) == 0) { smn[wv] = mnk; smx[wv] = mxk; }
    __syncthreads();
    if (threadIdx.x == 0) {
        unsigned bm = min(min(smn[0], smn[1]), min(smn[2], smn[3]));
        unsigned bx = max(max(smx[0], smx[1]), max(smx[2], smx[3]));
        if (use_atomic) {
            atomicMin(&ws[0], bm);
            atomicMax(&ws[1], bx);
        } else {
            ws[2 + 2 * blockIdx.x] = bm;
            ws[3 + 2 * blockIdx.x] = bx;
        }
    }
}

// Stage 2: one block reduces the MM_BLOCKS partial pairs -> ws[0], ws[1].
__global__ __launch_bounds__(256) void minmax_final(unsigned* __restrict__ ws,
                                                    int nblk) {
    unsigned mnk = 0xFFFFFFFFu, mxk = 0u;
    for (int i = threadIdx.x; i < nblk; i += 256) {
        mnk = min(mnk, ws[2 + 2 * i]);
        mxk = max(mxk, ws[3 + 2 * i]);
    }
    for (int off = 32; off; off >>= 1) {
        mnk = min(mnk, (unsigned)__shfl_down((int)mnk, off));
        mxk = max(mxk, (unsigned)__shfl_down((int)mxk, off));
    }
    __shared__ unsigned smn[4], smx[4];
    int wv = threadIdx.x >> 6;
    if ((threadIdx.x & 63) == 0) { smn[wv] = mnk; smx[wv] = mxk; }
    __syncthreads();
    if (threadIdx.x == 0) {
        ws[0] = min(min(smn[0], smn[1]), min(smn[2], smn[3]));
        ws[1] = max(max(smx[0], smx[1]), max(smx[2], smx[3]));
    }
}

__global__ __launch_bounds__(64) void recur_kernel(
        const float* __restrict__ in,
        const float* __restrict__ alpha,
        const float* __restrict__ beta,
        const unsigned* __restrict__ ws,
        float* __restrict__ out) {
    #pragma clang fp contract(off)   // bit-match numpy: no fma fusion
    __shared__ float lds[BROWS * LDS_STRIDE];   // 8448 B

    const int tid = threadIdx.x;
    const int r0 = blockIdx.x * BROWS;
    const float a = alpha[0];
    const float b = beta[0];
    const float mn = key2f(ws[0]);
    const float mx = key2f(ws[1]);
    const float denom = mx - mn;

    const float4* __restrict__ in4 = (const float4*)in;
    float4* __restrict__ out4 = (float4*)out;

    // Single-wave block: DS ops complete in order within a wave, so the
    // write->read->overwrite->read LDS sequence needs NO __syncthreads().
    // No barriers => no vmcnt(0) drains => loads/stores pipeline across tiles.

    #define LOADT(T, RR)                                                      \
        _Pragma("unroll")                                                     \
        for (int p = 0; p < 8; ++p) {                                         \
            int q = tid + p * 64;                                             \
            RR[p] = in4[(size_t)(r0 + (q >> 3)) * (NCOL / 4)                  \
                        + (T) * (TCOLS / 4) + (q & 7)];                       \
        }

    #define STAGE(RR)                                                         \
        _Pragma("unroll")                                                     \
        for (int p = 0; p < 8; ++p) {                                         \
            int q = tid + p * 64;                                             \
            float* dst = &lds[(q >> 3) * LDS_STRIDE + (q & 7) * 4];           \
            dst[0] = RR[p].x; dst[1] = RR[p].y;                               \
            dst[2] = RR[p].z; dst[3] = RR[p].w;                               \
        }

    #define COMPUTE()                                                         \
        {                                                                     \
            float* myrow = &lds[tid * LDS_STRIDE];                            \
            _Pragma("unroll")                                                 \
            for (int c = 0; c < TCOLS; ++c) {                                 \
                float x = myrow[c];                                           \
                float ov = w;                                                 \
                w = (w + a / w) - b * ((x - mn) / denom);                     \
                myrow[c] = ov;                                                \
            }                                                                 \
        }

    #define STORET(T)                                                         \
        _Pragma("unroll")                                                     \
        for (int p = 0; p < 8; ++p) {                                         \
            int q = tid + p * 64;                                             \
            const float* src = &lds[(q >> 3) * LDS_STRIDE + (q & 7) * 4];     \
            float4 v;                                                         \
            v.x = src[0]; v.y = src[1]; v.z = src[2]; v.w = src[3];           \
            out4[(size_t)(r0 + (q >> 3)) * (NCOL / 4)                         \
                 + (T) * (TCOLS / 4) + (q & 7)] = v;                          \
        }

    float w = 1.0f;
    float4 R[8], S[8];   // ping-pong prefetch registers (static indexing only)

    LOADT(0, R);
    for (int t = 0; t < NTILES; t += 2) {
        // even tile: consume R, prefetch into S
        STAGE(R);
        LOADT(t + 1, S);                 // t+1 <= 15 always (NTILES=16 even)
        COMPUTE();
        STORET(t);
        // odd tile: consume S, prefetch into R
        STAGE(S);
        if (t + 2 < NTILES) LOADT(t + 2, R);
        COMPUTE();
        STORET(t + 1);
    }

    #undef LOADT
    #undef STAGE
    #undef COMPUTE
    #undef STORET
}

extern "C" void kernel_launch(void* const* d_in, const int* in_sizes, int n_in,
                              void* d_out, int out_size, void* d_ws, size_t ws_size,
                              hipStream_t stream) {
    const float* in    = (const float*)d_in[0];
    const float* alpha = (const float*)d_in[1];
    const float* beta  = (const float*)d_in[2];
    float* out = (float*)d_out;
    unsigned* ws = (unsigned*)d_ws;

    const int n_elem = in_sizes[0];   // 67108864
    const int n4 = n_elem / 4;

    const bool two_stage =
        ws_size >= (size_t)(2 + 2 * MM_BLOCKS) * sizeof(unsigned);

    if (!two_stage) {
        hipLaunchKernelGGL(init_ws_kernel, dim3(1), dim3(1), 0, stream, ws);
    }
    hipLaunchKernelGGL(minmax_part, dim3(MM_BLOCKS), dim3(256), 0, stream,
                       (const float4*)in, ws, n4, two_stage ? 0 : 1);
    if (two_stage) {
        hipLaunchKernelGGL(minmax_final, dim3(1), dim3(256), 0, stream,
                           ws, MM_BLOCKS);
    }
    hipLaunchKernelGGL(recur_kernel, dim3(ROWS / BROWS), dim3(64), 0, stream,
                       in, alpha, beta, ws, out);
}

// Round 3
// 492.244 us; speedup vs baseline: 1.7382x; 1.0183x over previous
//
#include <hip/hip_runtime.h>

// l=32, m=4096, n=512 fp32. Rows (131072) independent; n strictly sequential.
//   x = (input - min) / (max - min);  w[0]=1; w[k] = w[k-1] + a/w[k-1] - b*x[k-1]
// NUMERICS: recurrence is chaotic (absmax 192 vs threshold 233) — keep the
// exact expression ((w + a/w) - b*((x-mn)/denom)), IEEE div, contract off.
//
// R1: LDS-staged tiles fixed HBM amplification (1.9GB -> 512MB). 855us.
// R2: two-stage minmax reduction (no contended atomics: 410->~55us) +
//     barrier-free single-wave recur with reg ping-pong prefetch. 501us.
// R3: (a) NONTEMPORAL output stores in recur: write-once data must not
//         write-allocate in L2/L3, or it evicts the input minmax just made
//         resident (input reads fall back to HBM). NT store via native clang
//         vector type (float4/HIP_vector_type is rejected by the builtin).
//     (b) prefetch loads issued BEFORE current-tile staging (earlier in
//         flight under the lgkmcnt-bound LDS/compute phase).
//     (c) minmax grid 2048x256 = full occupancy, exactly 32 float4/thread.

#define ROWS 131072
#define NCOL 512
#define BROWS 64          // rows per (single-wave) block
#define TCOLS 32          // tile width in floats
#define NTILES (NCOL / TCOLS)
#define LDS_STRIDE 33     // +1 pad: bank = (row + col) % 32 -> 2-way max (free)
#define MM_BLOCKS 2048    // minmax grid; partials = 2*MM_BLOCKS u32 in ws[2..]

typedef float vfloat4 __attribute__((ext_vector_type(4)));  // native vec for NT

__device__ __forceinline__ unsigned f2key(float f) {
    unsigned u = __float_as_uint(f);
    return (u & 0x80000000u) ? ~u : (u | 0x80000000u);  // monotone float->uint
}
__device__ __forceinline__ float key2f(unsigned k) {
    unsigned u = (k & 0x80000000u) ? (k & 0x7fffffffu) : ~k;
    return __uint_as_float(u);
}

__global__ void init_ws_kernel(unsigned* ws) {
    ws[0] = 0xFFFFFFFFu;  // min key accumulator (atomic-fallback path only)
    ws[1] = 0u;           // max key accumulator
}

// Stage 1: grid-stride scan, wave shfl-reduce, block LDS-reduce, then either
// write per-block partial (two-stage path) or one atomic pair (fallback).
__global__ __launch_bounds__(256) void minmax_part(
        const float4* __restrict__ in, unsigned* __restrict__ ws, int n4,
        int use_atomic) {
    unsigned mnk = 0xFFFFFFFFu, mxk = 0u;
    int idx = blockIdx.x * blockDim.x + threadIdx.x;
    int stride = gridDim.x * blockDim.x;   // 524288: n4/stride = 32 exactly
    int i = idx;
    for (; i + 3 * stride < n4; i += 4 * stride) {
        float4 v0 = in[i];
        float4 v1 = in[i + stride];
        float4 v2 = in[i + 2 * stride];
        float4 v3 = in[i + 3 * stride];
        unsigned k;
        k = f2key(v0.x); mnk = min(mnk, k); mxk = max(mxk, k);
        k = f2key(v0.y); mnk = min(mnk, k); mxk = max(mxk, k);
        k = f2key(v0.z); mnk = min(mnk, k); mxk = max(mxk, k);
        k = f2key(v0.w); mnk = min(mnk, k); mxk = max(mxk, k);
        k = f2key(v1.x); mnk = min(mnk, k); mxk = max(mxk, k);
        k = f2key(v1.y); mnk = min(mnk, k); mxk = max(mxk, k);
        k = f2key(v1.z); mnk = min(mnk, k); mxk = max(mxk, k);
        k = f2key(v1.w); mnk = min(mnk, k); mxk = max(mxk, k);
        k = f2key(v2.x); mnk = min(mnk, k); mxk = max(mxk, k);
        k = f2key(v2.y); mnk = min(mnk, k); mxk = max(mxk, k);
        k = f2key(v2.z); mnk = min(mnk, k); mxk = max(mxk, k);
        k = f2key(v2.w); mnk = min(mnk, k); mxk = max(mxk, k);
        k = f2key(v3.x); mnk = min(mnk, k); mxk = max(mxk, k);
        k = f2key(v3.y); mnk = min(mnk, k); mxk = max(mxk, k);
        k = f2key(v3.z); mnk = min(mnk, k); mxk = max(mxk, k);
        k = f2key(v3.w); mnk = min(mnk, k); mxk = max(mxk, k);
    }
    for (; i < n4; i += stride) {   // generic tail (empty at this shape)
        float4 v = in[i];
        unsigned k0 = f2key(v.x), k1 = f2key(v.y), k2 = f2key(v.z), k3 = f2key(v.w);
        mnk = min(mnk, min(min(k0, k1), min(k2, k3)));
        mxk = max(mxk, max(max(k0, k1), max(k2, k3)));
    }
    // wave (64-lane) reduce
    for (int off = 32; off; off >>= 1) {
        mnk = min(mnk, (unsigned)__shfl_down((int)mnk, off));
        mxk = max(mxk, (unsigned)__shfl_down((int)mxk, off));
    }
    __shared__ unsigned smn[4], smx[4];
    int wv = threadIdx.x >> 6;
    if ((threadIdx.x & 63) == 0) { smn[wv] = mnk; smx[wv] = mxk; }
    __syncthreads();
    if (threadIdx.x == 0) {
        unsigned bm = min(min(smn[0], smn[1]), min(smn[2], smn[3]));
        unsigned bx = max(max(smx[0], smx[1]), max(smx[2], smx[3]));
        if (use_atomic) {
            atomicMin(&ws[0], bm);
            atomicMax(&ws[1], bx);
        } else {
            ws[2 + 2 * blockIdx.x] = bm;
            ws[3 + 2 * blockIdx.x] = bx;
        }
    }
}

// Stage 2: one block reduces the MM_BLOCKS partial pairs -> ws[0], ws[1].
__global__ __launch_bounds__(256) void minmax_final(unsigned* __restrict__ ws,
                                                    int nblk) {
    unsigned mnk = 0xFFFFFFFFu, mxk = 0u;
    for (int i = threadIdx.x; i < nblk; i += 256) {
        mnk = min(mnk, ws[2 + 2 * i]);
        mxk = max(mxk, ws[3 + 2 * i]);
    }
    for (int off = 32; off; off >>= 1) {
        mnk = min(mnk, (unsigned)__shfl_down((int)mnk, off));
        mxk = max(mxk, (unsigned)__shfl_down((int)mxk, off));
    }
    __shared__ unsigned smn[4], smx[4];
    int wv = threadIdx.x >> 6;
    if ((threadIdx.x & 63) == 0) { smn[wv] = mnk; smx[wv] = mxk; }
    __syncthreads();
    if (threadIdx.x == 0) {
        ws[0] = min(min(smn[0], smn[1]), min(smn[2], smn[3]));
        ws[1] = max(max(smx[0], smx[1]), max(smx[2], smx[3]));
    }
}

__global__ __launch_bounds__(64) void recur_kernel(
        const float* __restrict__ in,
        const float* __restrict__ alpha,
        const float* __restrict__ beta,
        const unsigned* __restrict__ ws,
        float* __restrict__ out) {
    #pragma clang fp contract(off)   // bit-match numpy: no fma fusion
    __shared__ float lds[BROWS * LDS_STRIDE];   // 8448 B

    const int tid = threadIdx.x;
    const int r0 = blockIdx.x * BROWS;
    const float a = alpha[0];
    const float b = beta[0];
    const float mn = key2f(ws[0]);
    const float mx = key2f(ws[1]);
    const float denom = mx - mn;

    const float4* __restrict__ in4 = (const float4*)in;
    vfloat4* __restrict__ out4 = (vfloat4*)out;

    // Single-wave block: DS ops complete in order within a wave -> no barriers,
    // no vmcnt(0) drains; loads/stores pipeline freely across tiles.
    // Stores are NONTEMPORAL: output is write-once, never re-read; allocating
    // it in L2/L3 would evict the input that minmax_part just made resident.

    #define LOADT(T, RR)                                                      \
        _Pragma("unroll")                                                     \
        for (int p = 0; p < 8; ++p) {                                         \
            int q = tid + p * 64;                                             \
            RR[p] = in4[(size_t)(r0 + (q >> 3)) * (NCOL / 4)                  \
                        + (T) * (TCOLS / 4) + (q & 7)];                       \
        }

    #define STAGE(RR)                                                         \
        _Pragma("unroll")                                                     \
        for (int p = 0; p < 8; ++p) {                                         \
            int q = tid + p * 64;                                             \
            float* dst = &lds[(q >> 3) * LDS_STRIDE + (q & 7) * 4];           \
            dst[0] = RR[p].x; dst[1] = RR[p].y;                               \
            dst[2] = RR[p].z; dst[3] = RR[p].w;                               \
        }

    #define COMPUTE()                                                         \
        {                                                                     \
            float* myrow = &lds[tid * LDS_STRIDE];                            \
            _Pragma("unroll")                                                 \
            for (int c = 0; c < TCOLS; ++c) {                                 \
                float x = myrow[c];                                           \
                float ov = w;                                                 \
                w = (w + a / w) - b * ((x - mn) / denom);                     \
                myrow[c] = ov;                                                \
            }                                                                 \
        }

    #define STORET(T)                                                         \
        _Pragma("unroll")                                                     \
        for (int p = 0; p < 8; ++p) {                                         \
            int q = tid + p * 64;                                             \
            const float* src = &lds[(q >> 3) * LDS_STRIDE + (q & 7) * 4];     \
            vfloat4 v;                                                        \
            v.x = src[0]; v.y = src[1]; v.z = src[2]; v.w = src[3];           \
            __builtin_nontemporal_store(                                      \
                v, &out4[(size_t)(r0 + (q >> 3)) * (NCOL / 4)                 \
                         + (T) * (TCOLS / 4) + (q & 7)]);                     \
        }

    float w = 1.0f;
    float4 R[8], S[8];   // ping-pong prefetch registers (static indexing only)

    LOADT(0, R);
    for (int t = 0; t < NTILES; t += 2) {
        // even tile: issue next-tile loads FIRST (earlier in flight), then
        // stage R (vmcnt wait leaves S's loads outstanding), compute, store.
        LOADT(t + 1, S);                 // t+1 <= 15 always (NTILES=16 even)
        STAGE(R);
        COMPUTE();
        STORET(t);
        // odd tile: same with roles swapped
        if (t + 2 < NTILES) LOADT(t + 2, R);
        STAGE(S);
        COMPUTE();
        STORET(t + 1);
    }

    #undef LOADT
    #undef STAGE
    #undef COMPUTE
    #undef STORET
}

extern "C" void kernel_launch(void* const* d_in, const int* in_sizes, int n_in,
                              void* d_out, int out_size, void* d_ws, size_t ws_size,
                              hipStream_t stream) {
    const float* in    = (const float*)d_in[0];
    const float* alpha = (const float*)d_in[1];
    const float* beta  = (const float*)d_in[2];
    float* out = (float*)d_out;
    unsigned* ws = (unsigned*)d_ws;

    const int n_elem = in_sizes[0];   // 67108864
    const int n4 = n_elem / 4;

    const bool two_stage =
        ws_size >= (size_t)(2 + 2 * MM_BLOCKS) * sizeof(unsigned);

    if (!two_stage) {
        hipLaunchKernelGGL(init_ws_kernel, dim3(1), dim3(1), 0, stream, ws);
    }
    hipLaunchKernelGGL(minmax_part, dim3(MM_BLOCKS), dim3(256), 0, stream,
                       (const float4*)in, ws, n4, two_stage ? 0 : 1);
    if (two_stage) {
        hipLaunchKernelGGL(minmax_final, dim3(1), dim3(256), 0, stream,
                           ws, MM_BLOCKS);
    }
    hipLaunchKernelGGL(recur_kernel, dim3(ROWS / BROWS), dim3(64), 0, stream,
                       in, alpha, beta, ws, out);
}